// Round 13
// baseline (182.456 us; speedup 1.0000x reference)
//
#include <hip/hip_runtime.h>
#include <stdint.h>

typedef _Float16 f16;
typedef _Float16 f16x2 __attribute__((ext_vector_type(2)));
typedef _Float16 f16x8 __attribute__((ext_vector_type(8)));
typedef float f32x4 __attribute__((ext_vector_type(4)));
typedef float f32x16 __attribute__((ext_vector_type(16)));
typedef uint32_t u32x4 __attribute__((ext_vector_type(4)));

#define B_   4
#define S_   2048
#define E_   1024
#define H_   16
#define HD_  64
#define BH_  (B_ * H_)

template <int N> struct IC { static constexpr int v = N; };

// ---------------------------------------------------------------- helpers
__device__ __forceinline__ void async_lds16(const void* g, void* l) {
    __builtin_amdgcn_global_load_lds(
        (__attribute__((address_space(1))) void*)(uintptr_t)g,
        (__attribute__((address_space(3))) void*)(uint32_t)(uintptr_t)l,
        16, 0, 0);
}

// ---------------------------------------------------------------- fp32 -> fp16
__global__ __launch_bounds__(256)
void cvt_f32_to_f16(const float* __restrict__ in, f16* __restrict__ out, int n8) {
    int i = blockIdx.x * 256 + threadIdx.x;
    if (i >= n8) return;
    const float4* p = (const float4*)in;
    float4 a = p[2 * i], b = p[2 * i + 1];
    f16x8 o;
    o[0] = (f16)a.x; o[1] = (f16)a.y; o[2] = (f16)a.z; o[3] = (f16)a.w;
    o[4] = (f16)b.x; o[5] = (f16)b.y; o[6] = (f16)b.z; o[7] = (f16)b.w;
    *(f16x8*)(out + 8 * (long)i) = o;
}

// ---------------------------------------------------------------- GEMM  C = A[M,K] * B[N,K]^T
// v4 = v2 core (proven: 128x128 tile, 16x16x32, static ping-pong, staging
// XOR-swizzle, v-transpose epilogue) + optional fused fp32 A-source:
// FUSEA=1 stages A from f32 x via reg-load + v_cvt + ds_write (same LDS
// layout/dest as global_load_lds produced), placed after compute so the
// load latency is TLP-hidden. Kills the separate x-cvt kernel + xb traffic.
template <int MODE, int FUSEA>
__global__ __launch_bounds__(256)
void gemm_bt(const f16* __restrict__ A, const float* __restrict__ Af32,
             const f16* __restrict__ Bm,
             const float* __restrict__ bias, float* __restrict__ Cf,
             f16* __restrict__ qo, f16* __restrict__ ko, f16* __restrict__ vto,
             int M, int N, int K)
{
    __shared__ __align__(16) f16 As[2][128 * 32];
    __shared__ __align__(16) f16 Bs[2][128 * 32];
    const int tid = threadIdx.x;
    const int wave = tid >> 6, lane = tid & 63;
    const int lo = lane & 15, hi = lane >> 4;
    const int ntn = N >> 7;
    const int tm = blockIdx.x / ntn, tn = blockIdx.x % ntn;
    const long bm0 = (long)tm << 7, bn0 = (long)tn << 7;
    const int wr = (wave >> 1) << 6, wc = (wave & 1) << 6;

    int srow[2], sxc[2];
#pragma unroll
    for (int p = 0; p < 2; ++p) {
        const int c = p * 256 + tid;
        srow[p] = c >> 2;
        sxc[p]  = (((c & 3) ^ ((c >> 3) & 3))) * 8;
    }

    // B staging: always global_load_lds from f16
#define GSTAGE_B(BUF, K0)  do {                                                   \
    _Pragma("unroll")                                                             \
    for (int p = 0; p < 2; ++p)                                                   \
        async_lds16(Bm + (bn0 + srow[p]) * K + (K0) + sxc[p],                     \
                    &Bs[BUF][(p * 256 + wave * 64) * 8]);                         \
    } while (0)

    // A staging, f16 path
#define GSTAGE_A16(BUF, K0)  do {                                                 \
    _Pragma("unroll")                                                             \
    for (int p = 0; p < 2; ++p)                                                   \
        async_lds16(A + (bm0 + srow[p]) * K + (K0) + sxc[p],                      \
                    &As[BUF][(p * 256 + wave * 64) * 8]);                         \
    } while (0)

    // A staging, fused f32->f16 path (same dest layout: chunk c -> c*8 f16)
#define GSTAGE_A32(BUF, K0)  do {                                                 \
    _Pragma("unroll")                                                             \
    for (int p = 0; p < 2; ++p) {                                                 \
        const float4* xs = (const float4*)&Af32[(bm0 + srow[p]) * K + (K0) + sxc[p]]; \
        float4 a = xs[0], b = xs[1];                                              \
        f16x8 o;                                                                  \
        o[0] = (f16)a.x; o[1] = (f16)a.y; o[2] = (f16)a.z; o[3] = (f16)a.w;       \
        o[4] = (f16)b.x; o[5] = (f16)b.y; o[6] = (f16)b.z; o[7] = (f16)b.w;       \
        *(f16x8*)&As[BUF][(p * 256 + tid) * 8] = o;                               \
    } } while (0)

    f32x4 acc[4][4] = {};

    auto compute = [&](auto bufc) {
        constexpr int BUF = decltype(bufc)::v;
        f16x8 af[4], bf[4];
#pragma unroll
        for (int mi = 0; mi < 4; ++mi) {
            const int row = wr + mi * 16 + lo;
            af[mi] = *(const f16x8*)&As[BUF][row * 32 + ((hi ^ ((row >> 1) & 3)) * 8)];
        }
#pragma unroll
        for (int ni = 0; ni < 4; ++ni) {
            const int row = wc + ni * 16 + lo;
            bf[ni] = *(const f16x8*)&Bs[BUF][row * 32 + ((hi ^ ((row >> 1) & 3)) * 8)];
        }
        __builtin_amdgcn_s_setprio(1);
#pragma unroll
        for (int mi = 0; mi < 4; ++mi)
#pragma unroll
            for (int ni = 0; ni < 4; ++ni)
                acc[mi][ni] = __builtin_amdgcn_mfma_f32_16x16x32_f16(
                    af[mi], bf[ni], acc[mi][ni], 0, 0, 0);
        __builtin_amdgcn_s_setprio(0);
    };

    // prologue
    GSTAGE_B(0, 0);
    if (FUSEA) GSTAGE_A32(0, 0); else GSTAGE_A16(0, 0);
    __syncthreads();
    for (int k0 = 0; k0 < K; k0 += 64) {
        GSTAGE_B(1, k0 + 32);
        if (!FUSEA) GSTAGE_A16(1, k0 + 32);
        compute(IC<0>{});
        if (FUSEA) GSTAGE_A32(1, k0 + 32);   // after compute: latency TLP-hidden
        __syncthreads();
        if (k0 + 64 < K) {
            GSTAGE_B(0, k0 + 64);
            if (!FUSEA) GSTAGE_A16(0, k0 + 64);
        }
        compute(IC<1>{});
        if (FUSEA && k0 + 64 < K) GSTAGE_A32(0, k0 + 64);
        __syncthreads();
    }
#undef GSTAGE_B
#undef GSTAGE_A16
#undef GSTAGE_A32

    if (MODE == 1) {
#pragma unroll
        for (int mi = 0; mi < 4; ++mi)
#pragma unroll
            for (int ni = 0; ni < 4; ++ni)
#pragma unroll
                for (int j = 0; j < 4; ++j) {
                    const long r  = bm0 + wr + mi * 16 + 4 * hi + j;
                    const int  cn = (int)bn0 + wc + ni * 16 + lo;
                    Cf[r * N + cn] = acc[mi][ni][j] + bias[cn];
                }
        return;
    }

    const int which = (int)(bn0 >> 10);
    if (which < 2) {
#pragma unroll
        for (int mi = 0; mi < 4; ++mi)
#pragma unroll
            for (int ni = 0; ni < 4; ++ni)
#pragma unroll
                for (int j = 0; j < 4; ++j) {
                    const long r  = bm0 + wr + mi * 16 + 4 * hi + j;
                    const int  cn = (int)bn0 + wc + ni * 16 + lo;
                    const int  e = cn & 1023, h = e >> 6, d = e & 63;
                    const int  b = (int)(r >> 11), s = (int)(r & 2047);
                    const long bh = (long)b * H_ + h;
                    const f16 hv = (f16)(acc[mi][ni][j] + bias[cn]);
                    if (which == 0) qo[(bh * S_ + s) * HD_ + d] = hv;
                    else            ko[(bh * S_ + s) * HD_ + d] = hv;
                }
    } else {
        f16* T = (wave < 2) ? ((f16*)As) + wave * 4096 : ((f16*)Bs) + (wave - 2) * 4096;
#pragma unroll
        for (int ni = 0; ni < 4; ++ni) {
            const int dl = ni * 16 + lo;
            const int dx = dl & 7;
#pragma unroll
            for (int mi = 0; mi < 4; ++mi)
#pragma unroll
                for (int j = 0; j < 4; ++j) {
                    const int sl = mi * 16 + 4 * hi + j;
                    const int cn = (int)bn0 + wc + ni * 16 + lo;
                    T[dl * 64 + ((((sl >> 3) ^ dx) << 3) | (sl & 7))] =
                        (f16)(acc[mi][ni][j] + bias[cn]);
                }
        }
        const int b = (int)(bm0 >> 11);
        const int sbase = (int)(bm0 & 2047) + wr;
        const int h = ((int)(bn0 & 1023) + wc) >> 6;
        const long vbase = (long)(b * H_ + h) * HD_;
#pragma unroll
        for (int it = 0; it < 8; ++it) {
            const int d = it * 8 + (lane >> 3);
            const int schunk = lane & 7;
            u32x4 val = *(const u32x4*)&T[d * 64 + ((schunk ^ (d & 7)) << 3)];
            *(u32x4*)&vto[(vbase + d) * S_ + sbase + schunk * 8] = val;
        }
    }
}

// ---------------------------------------------------------------- causal flash attention
// v9 (unchanged): 32x32 swapped QK, in-register P, chunk-major LDS, static
// ping-pong, strip pairing, raw v_exp_f32 softmax, dot2 row-sums.
__global__ __launch_bounds__(256)
void attn_fwd(const f16* __restrict__ qb, const f16* __restrict__ kb,
              const f16* __restrict__ vtb, f16* __restrict__ ob)
{
    __shared__ __align__(16) f16 Ks[2][64 * 64];   // chunk-major: [c=d/8][kv]
    __shared__ __align__(16) f16 Vs[2][64 * 64];   // chunk-major: [c=kv/8][d]
    const int tid = threadIdx.x, wave = tid >> 6, lane = tid & 63;
    const int q32 = lane & 31, h2 = lane >> 5;
    const int bh = blockIdx.y;
    const int qtA = blockIdx.x;          // 0..7
    const int qtB = 15 - qtA;            // 8..15
    const int qwA = qtA * 128 + wave * 32;
    const int qwB = qtB * 128 + wave * 32;
    const long krow0 = (long)bh * S_;
    const long vrow0 = (long)bh * HD_;

#define STAGE(BUF, KV)  do {                                                      \
    _Pragma("unroll")                                                             \
    for (int p = 0; p < 2; ++p) {                                                 \
        const int n = p * 256 + tid;                                              \
        const int base = (p * 256 + wave * 64) * 8;                               \
        async_lds16(kb  + (krow0 + (KV) + (n & 63)) * HD_ + (n >> 6) * 8, &Ks[BUF][base]); \
        async_lds16(vtb + (vrow0 + (n & 63)) * S_ + (KV) + (n >> 6) * 8, &Vs[BUF][base]);  \
    } } while (0)

    f16x8 qfA[4], qfB[4];
    const f16 sch = (f16)0.1803368801f;
#pragma unroll
    for (int kkq = 0; kkq < 4; ++kkq) {
        qfA[kkq] = *(const f16x8*)&qb[(krow0 + qwA + q32) * HD_ + kkq * 16 + h2 * 8];
        qfB[kkq] = *(const f16x8*)&qb[(krow0 + qwB + q32) * HD_ + kkq * 16 + h2 * 8];
#pragma unroll
        for (int e = 0; e < 8; ++e) { qfA[kkq][e] *= sch; qfB[kkq][e] *= sch; }
    }

    f32x16 oaccA[2] = {}, oaccB[2] = {};
    float lA = 0.f, lB = 0.f;
    const f16x2 ones2 = { (f16)1.0f, (f16)1.0f };

    auto computeS = [&](auto bufc, auto spc, int t) {
        constexpr int BUF = decltype(bufc)::v;
        constexpr int SP  = decltype(spc)::v;
        const int qw = SP ? qwB : qwA;
        const f16x8* qf = SP ? qfB : qfA;
        f32x16* oacc = SP ? oaccB : oaccA;
        float& l_part = SP ? lB : lA;
        const int kv0 = t * 64;
        if (kv0 > qw + 31) return;     // strip done (fully masked)
        const int qg = qw + q32;

        f32x16 sc[2] = {};
        __builtin_amdgcn_s_setprio(1);
#pragma unroll
        for (int kkq = 0; kkq < 4; ++kkq)
#pragma unroll
            for (int ni = 0; ni < 2; ++ni) {
                f16x8 kf = *(const f16x8*)&Ks[BUF][(((kkq * 2 + h2) * 64) + ni * 32 + q32) * 8];
                sc[ni] = __builtin_amdgcn_mfma_f32_32x32x16_f16(kf, qf[kkq], sc[ni], 0, 0, 0);
            }
        __builtin_amdgcn_s_setprio(0);

        const bool maskp = (kv0 + 63) > qw;
#pragma unroll
        for (int ni = 0; ni < 2; ++ni)
#pragma unroll
            for (int r = 0; r < 16; ++r) {
                float p = __builtin_amdgcn_exp2f(sc[ni][r]);
                const int kvg = kv0 + ni * 32 + (r & 3) + 8 * (r >> 2) + 4 * h2;
                if (maskp && kvg > qg) p = 0.0f;
                sc[ni][r] = p;
            }

        __builtin_amdgcn_s_setprio(1);
#pragma unroll
        for (int ni = 0; ni < 2; ++ni) {
            uint32_t u[8];
#pragma unroll
            for (int m = 0; m < 8; ++m) {
                auto hp = __builtin_amdgcn_cvt_pkrtz(sc[ni][2 * m], sc[ni][2 * m + 1]);
                u[m] = __builtin_bit_cast(uint32_t, hp);
                l_part = __builtin_amdgcn_fdot2(__builtin_bit_cast(f16x2, u[m]), ones2, l_part, false);
            }
#pragma unroll
            for (int kkv = 0; kkv < 2; ++kkv) {
                auto sA = __builtin_amdgcn_permlane32_swap(u[4 * kkv + 0], u[4 * kkv + 2], false, false);
                auto sB = __builtin_amdgcn_permlane32_swap(u[4 * kkv + 1], u[4 * kkv + 3], false, false);
                u32x4 uv = { (uint32_t)sA[0], (uint32_t)sB[0], (uint32_t)sA[1], (uint32_t)sB[1] };
                f16x8 pf = __builtin_bit_cast(f16x8, uv);
                const int kg = ni * 2 + kkv;
#pragma unroll
                for (int dh = 0; dh < 2; ++dh) {
                    f16x8 vf = *(const f16x8*)&Vs[BUF][(((kg * 2 + h2) * 64) + dh * 32 + q32) * 8];
                    oacc[dh] = __builtin_amdgcn_mfma_f32_32x32x16_f16(pf, vf, oacc[dh], 0, 0, 0);
                }
            }
        }
        __builtin_amdgcn_s_setprio(0);
    };

    const int ntB = 2 * (qtB + 1);    // 18..32, even; strip B is the long one
    STAGE(0, 0);
    __syncthreads();
    for (int t = 0; t < ntB; t += 2) {
        STAGE(1, (t + 1) * 64);
        computeS(IC<0>{}, IC<0>{}, t);
        computeS(IC<0>{}, IC<1>{}, t);
        __syncthreads();
        if (t + 2 < ntB) STAGE(0, (t + 2) * 64);
        computeS(IC<1>{}, IC<0>{}, t + 1);
        computeS(IC<1>{}, IC<1>{}, t + 1);
        __syncthreads();
    }
#undef STAGE

    const int b = bh >> 4, h = bh & 15;
    const float invA = 1.0f / (lA + __shfl_xor(lA, 32));
    const float invB = 1.0f / (lB + __shfl_xor(lB, 32));
#pragma unroll
    for (int r = 0; r < 16; ++r) {
        const int crow = (r & 3) + 8 * (r >> 2) + 4 * h2;
        const float irA = __shfl(invA, crow);
        const float irB = __shfl(invB, crow);
#pragma unroll
        for (int dh = 0; dh < 2; ++dh) {
            ob[((long)b * S_ + qwA + crow) * E_ + h * HD_ + dh * 32 + q32] = (f16)(oaccA[dh][r] * irA);
            ob[((long)b * S_ + qwB + crow) * E_ + h * HD_ + dh * 32 + q32] = (f16)(oaccB[dh][r] * irB);
        }
    }
}

// ---------------------------------------------------------------- launch
extern "C" void kernel_launch(void* const* d_in, const int* in_sizes, int n_in,
                              void* d_out, int out_size, void* d_ws, size_t ws_size,
                              hipStream_t stream)
{
    (void)in_sizes; (void)n_in; (void)out_size; (void)ws_size;
    const float* x  = (const float*)d_in[0];
    const float* w1 = (const float*)d_in[1];
    const float* b1 = (const float*)d_in[2];
    const float* w2 = (const float*)d_in[3];
    const float* b2 = (const float*)d_in[4];
    float* out = (float*)d_out;

    char* ws = (char*)d_ws;
    f16* w1b = (f16*)ws;  ws += (size_t)3072 * 1024 * 2;
    f16* w2b = (f16*)ws;  ws += (size_t)1024 * 1024 * 2;
    f16* qb  = (f16*)ws;  ws += (size_t)BH_ * S_ * HD_ * 2;
    f16* kb  = (f16*)ws;  ws += (size_t)BH_ * S_ * HD_ * 2;
    f16* vtb = (f16*)ws;  ws += (size_t)BH_ * S_ * HD_ * 2;
    f16* ao  = (f16*)ws;  ws += (size_t)8192 * 1024 * 2;

    cvt_f32_to_f16<<<dim3(3072 * 1024 / 8 / 256), dim3(256), 0, stream>>>(w1, w1b, 3072 * 1024 / 8);
    cvt_f32_to_f16<<<dim3(1024 * 1024 / 8 / 256), dim3(256), 0, stream>>>(w2, w2b, 1024 * 1024 / 8);

    gemm_bt<0, 1><<<dim3(64 * 24), dim3(256), 0, stream>>>(
        nullptr, x, w1b, b1, nullptr, qb, kb, vtb, 8192, 3072, 1024);

    attn_fwd<<<dim3(8, 64), dim3(256), 0, stream>>>(qb, kb, vtb, ao);

    gemm_bt<1, 0><<<dim3(64 * 8), dim3(256), 0, stream>>>(
        ao, nullptr, w2b, b2, out, nullptr, nullptr, nullptr, 8192, 1024, 1024);
}

// Round 14
// 179.034 us; speedup vs baseline: 1.0191x; 1.0191x over previous
//
#include <hip/hip_runtime.h>
#include <stdint.h>

typedef _Float16 f16;
typedef _Float16 f16x2 __attribute__((ext_vector_type(2)));
typedef _Float16 f16x8 __attribute__((ext_vector_type(8)));
typedef float f32x4 __attribute__((ext_vector_type(4)));
typedef float f32x16 __attribute__((ext_vector_type(16)));
typedef uint32_t u32x4 __attribute__((ext_vector_type(4)));

#define B_   4
#define S_   2048
#define E_   1024
#define H_   16
#define HD_  64
#define BH_  (B_ * H_)

template <int N> struct IC { static constexpr int v = N; };

// ---------------------------------------------------------------- helpers
__device__ __forceinline__ void async_lds16(const void* g, void* l) {
    __builtin_amdgcn_global_load_lds(
        (__attribute__((address_space(1))) void*)(uintptr_t)g,
        (__attribute__((address_space(3))) void*)(uint32_t)(uintptr_t)l,
        16, 0, 0);
}

// ---------------------------------------------------------------- fp32 -> fp16
__global__ __launch_bounds__(256)
void cvt_f32_to_f16(const float* __restrict__ in, f16* __restrict__ out, int n8) {
    int i = blockIdx.x * 256 + threadIdx.x;
    if (i >= n8) return;
    const float4* p = (const float4*)in;
    float4 a = p[2 * i], b = p[2 * i + 1];
    f16x8 o;
    o[0] = (f16)a.x; o[1] = (f16)a.y; o[2] = (f16)a.z; o[3] = (f16)a.w;
    o[4] = (f16)b.x; o[5] = (f16)b.y; o[6] = (f16)b.z; o[7] = (f16)b.w;
    *(f16x8*)(out + 8 * (long)i) = o;
}

// ---------------------------------------------------------------- GEMM  C = A[M,K] * B[N,K]^T
// v5 = v2 core (proven 75.4us: 128x128, 16x16x32, static ping-pong, staging
// XOR-swizzle, v-transpose epilogue) + T14-CORRECT fused fp32 A-source:
// A32_LOAD (global->regs) issued BEFORE the prior barrier (one compute +
// barrier of latency coverage); A32_WRITE (cvt+ds_write) after the next
// compute into the buffer the other phase reads. Round-13's failure was
// issuing load+write together post-compute -> zero coverage.
template <int MODE, int FUSEA>
__global__ __launch_bounds__(256)
void gemm_bt(const f16* __restrict__ A, const float* __restrict__ Af32,
             const f16* __restrict__ Bm,
             const float* __restrict__ bias, float* __restrict__ Cf,
             f16* __restrict__ qo, f16* __restrict__ ko, f16* __restrict__ vto,
             int M, int N, int K)
{
    __shared__ __align__(16) f16 As[2][128 * 32];
    __shared__ __align__(16) f16 Bs[2][128 * 32];
    const int tid = threadIdx.x;
    const int wave = tid >> 6, lane = tid & 63;
    const int lo = lane & 15, hi = lane >> 4;
    const int ntn = N >> 7;
    const int tm = blockIdx.x / ntn, tn = blockIdx.x % ntn;
    const long bm0 = (long)tm << 7, bn0 = (long)tn << 7;
    const int wr = (wave >> 1) << 6, wc = (wave & 1) << 6;

    int srow[2], sxc[2];
#pragma unroll
    for (int p = 0; p < 2; ++p) {
        const int c = p * 256 + tid;
        srow[p] = c >> 2;
        sxc[p]  = (((c & 3) ^ ((c >> 3) & 3))) * 8;
    }

#define GSTAGE_B(BUF, K0)  do {                                                   \
    _Pragma("unroll")                                                             \
    for (int p = 0; p < 2; ++p)                                                   \
        async_lds16(Bm + (bn0 + srow[p]) * K + (K0) + sxc[p],                     \
                    &Bs[BUF][(p * 256 + wave * 64) * 8]);                         \
    } while (0)

#define GSTAGE_A16(BUF, K0)  do {                                                 \
    _Pragma("unroll")                                                             \
    for (int p = 0; p < 2; ++p)                                                   \
        async_lds16(A + (bm0 + srow[p]) * K + (K0) + sxc[p],                      \
                    &As[BUF][(p * 256 + wave * 64) * 8]);                         \
    } while (0)

    float4 ald[4];   // in-flight f32 A data (FUSEA), 16 VGPR

#define A32_LOAD(K0)  do {                                                        \
    _Pragma("unroll")                                                             \
    for (int p = 0; p < 2; ++p) {                                                 \
        const float4* xs = (const float4*)&Af32[(bm0 + srow[p]) * K + (K0) + sxc[p]]; \
        ald[2 * p] = xs[0]; ald[2 * p + 1] = xs[1];                               \
    } } while (0)

#define A32_WRITE(BUF)  do {                                                      \
    _Pragma("unroll")                                                             \
    for (int p = 0; p < 2; ++p) {                                                 \
        float4 a = ald[2 * p], b = ald[2 * p + 1];                                \
        f16x8 o;                                                                  \
        o[0] = (f16)a.x; o[1] = (f16)a.y; o[2] = (f16)a.z; o[3] = (f16)a.w;       \
        o[4] = (f16)b.x; o[5] = (f16)b.y; o[6] = (f16)b.z; o[7] = (f16)b.w;       \
        *(f16x8*)&As[BUF][(p * 256 + tid) * 8] = o;                               \
    } } while (0)

    f32x4 acc[4][4] = {};

    auto compute = [&](auto bufc) {
        constexpr int BUF = decltype(bufc)::v;
        f16x8 af[4], bf[4];
#pragma unroll
        for (int mi = 0; mi < 4; ++mi) {
            const int row = wr + mi * 16 + lo;
            af[mi] = *(const f16x8*)&As[BUF][row * 32 + ((hi ^ ((row >> 1) & 3)) * 8)];
        }
#pragma unroll
        for (int ni = 0; ni < 4; ++ni) {
            const int row = wc + ni * 16 + lo;
            bf[ni] = *(const f16x8*)&Bs[BUF][row * 32 + ((hi ^ ((row >> 1) & 3)) * 8)];
        }
        __builtin_amdgcn_s_setprio(1);
#pragma unroll
        for (int mi = 0; mi < 4; ++mi)
#pragma unroll
            for (int ni = 0; ni < 4; ++ni)
                acc[mi][ni] = __builtin_amdgcn_mfma_f32_16x16x32_f16(
                    af[mi], bf[ni], acc[mi][ni], 0, 0, 0);
        __builtin_amdgcn_s_setprio(0);
    };

    // prologue: buf0 staged synchronously; A-load for buf1 issued BEFORE barrier
    GSTAGE_B(0, 0);
    if (FUSEA) { A32_LOAD(0); A32_WRITE(0); A32_LOAD(32); }
    else GSTAGE_A16(0, 0);
    __syncthreads();
    for (int k0 = 0; k0 < K; k0 += 64) {
        GSTAGE_B(1, k0 + 32);
        if (!FUSEA) GSTAGE_A16(1, k0 + 32);
        compute(IC<0>{});
        if (FUSEA) { A32_WRITE(1); if (k0 + 64 < K) A32_LOAD(k0 + 64); }
        __syncthreads();
        if (k0 + 64 < K) {
            GSTAGE_B(0, k0 + 64);
            if (!FUSEA) GSTAGE_A16(0, k0 + 64);
        }
        compute(IC<1>{});
        if (FUSEA && k0 + 64 < K) { A32_WRITE(0); if (k0 + 96 < K) A32_LOAD(k0 + 96); }
        __syncthreads();
    }
#undef GSTAGE_B
#undef GSTAGE_A16
#undef A32_LOAD
#undef A32_WRITE

    if (MODE == 1) {
#pragma unroll
        for (int mi = 0; mi < 4; ++mi)
#pragma unroll
            for (int ni = 0; ni < 4; ++ni)
#pragma unroll
                for (int j = 0; j < 4; ++j) {
                    const long r  = bm0 + wr + mi * 16 + 4 * hi + j;
                    const int  cn = (int)bn0 + wc + ni * 16 + lo;
                    Cf[r * N + cn] = acc[mi][ni][j] + bias[cn];
                }
        return;
    }

    const int which = (int)(bn0 >> 10);
    if (which < 2) {
#pragma unroll
        for (int mi = 0; mi < 4; ++mi)
#pragma unroll
            for (int ni = 0; ni < 4; ++ni)
#pragma unroll
                for (int j = 0; j < 4; ++j) {
                    const long r  = bm0 + wr + mi * 16 + 4 * hi + j;
                    const int  cn = (int)bn0 + wc + ni * 16 + lo;
                    const int  e = cn & 1023, h = e >> 6, d = e & 63;
                    const int  b = (int)(r >> 11), s = (int)(r & 2047);
                    const long bh = (long)b * H_ + h;
                    const f16 hv = (f16)(acc[mi][ni][j] + bias[cn]);
                    if (which == 0) qo[(bh * S_ + s) * HD_ + d] = hv;
                    else            ko[(bh * S_ + s) * HD_ + d] = hv;
                }
    } else {
        f16* T = (wave < 2) ? ((f16*)As) + wave * 4096 : ((f16*)Bs) + (wave - 2) * 4096;
#pragma unroll
        for (int ni = 0; ni < 4; ++ni) {
            const int dl = ni * 16 + lo;
            const int dx = dl & 7;
#pragma unroll
            for (int mi = 0; mi < 4; ++mi)
#pragma unroll
                for (int j = 0; j < 4; ++j) {
                    const int sl = mi * 16 + 4 * hi + j;
                    const int cn = (int)bn0 + wc + ni * 16 + lo;
                    T[dl * 64 + ((((sl >> 3) ^ dx) << 3) | (sl & 7))] =
                        (f16)(acc[mi][ni][j] + bias[cn]);
                }
        }
        const int b = (int)(bm0 >> 11);
        const int sbase = (int)(bm0 & 2047) + wr;
        const int h = ((int)(bn0 & 1023) + wc) >> 6;
        const long vbase = (long)(b * H_ + h) * HD_;
#pragma unroll
        for (int it = 0; it < 8; ++it) {
            const int d = it * 8 + (lane >> 3);
            const int schunk = lane & 7;
            u32x4 val = *(const u32x4*)&T[d * 64 + ((schunk ^ (d & 7)) << 3)];
            *(u32x4*)&vto[(vbase + d) * S_ + sbase + schunk * 8] = val;
        }
    }
}

// ---------------------------------------------------------------- causal flash attention
// v9 (unchanged): 32x32 swapped QK, in-register P, chunk-major LDS, static
// ping-pong, strip pairing, raw v_exp_f32 softmax, dot2 row-sums.
__global__ __launch_bounds__(256)
void attn_fwd(const f16* __restrict__ qb, const f16* __restrict__ kb,
              const f16* __restrict__ vtb, f16* __restrict__ ob)
{
    __shared__ __align__(16) f16 Ks[2][64 * 64];   // chunk-major: [c=d/8][kv]
    __shared__ __align__(16) f16 Vs[2][64 * 64];   // chunk-major: [c=kv/8][d]
    const int tid = threadIdx.x, wave = tid >> 6, lane = tid & 63;
    const int q32 = lane & 31, h2 = lane >> 5;
    const int bh = blockIdx.y;
    const int qtA = blockIdx.x;          // 0..7
    const int qtB = 15 - qtA;            // 8..15
    const int qwA = qtA * 128 + wave * 32;
    const int qwB = qtB * 128 + wave * 32;
    const long krow0 = (long)bh * S_;
    const long vrow0 = (long)bh * HD_;

#define STAGE(BUF, KV)  do {                                                      \
    _Pragma("unroll")                                                             \
    for (int p = 0; p < 2; ++p) {                                                 \
        const int n = p * 256 + tid;                                              \
        const int base = (p * 256 + wave * 64) * 8;                               \
        async_lds16(kb  + (krow0 + (KV) + (n & 63)) * HD_ + (n >> 6) * 8, &Ks[BUF][base]); \
        async_lds16(vtb + (vrow0 + (n & 63)) * S_ + (KV) + (n >> 6) * 8, &Vs[BUF][base]);  \
    } } while (0)

    f16x8 qfA[4], qfB[4];
    const f16 sch = (f16)0.1803368801f;
#pragma unroll
    for (int kkq = 0; kkq < 4; ++kkq) {
        qfA[kkq] = *(const f16x8*)&qb[(krow0 + qwA + q32) * HD_ + kkq * 16 + h2 * 8];
        qfB[kkq] = *(const f16x8*)&qb[(krow0 + qwB + q32) * HD_ + kkq * 16 + h2 * 8];
#pragma unroll
        for (int e = 0; e < 8; ++e) { qfA[kkq][e] *= sch; qfB[kkq][e] *= sch; }
    }

    f32x16 oaccA[2] = {}, oaccB[2] = {};
    float lA = 0.f, lB = 0.f;
    const f16x2 ones2 = { (f16)1.0f, (f16)1.0f };

    auto computeS = [&](auto bufc, auto spc, int t) {
        constexpr int BUF = decltype(bufc)::v;
        constexpr int SP  = decltype(spc)::v;
        const int qw = SP ? qwB : qwA;
        const f16x8* qf = SP ? qfB : qfA;
        f32x16* oacc = SP ? oaccB : oaccA;
        float& l_part = SP ? lB : lA;
        const int kv0 = t * 64;
        if (kv0 > qw + 31) return;     // strip done (fully masked)
        const int qg = qw + q32;

        f32x16 sc[2] = {};
        __builtin_amdgcn_s_setprio(1);
#pragma unroll
        for (int kkq = 0; kkq < 4; ++kkq)
#pragma unroll
            for (int ni = 0; ni < 2; ++ni) {
                f16x8 kf = *(const f16x8*)&Ks[BUF][(((kkq * 2 + h2) * 64) + ni * 32 + q32) * 8];
                sc[ni] = __builtin_amdgcn_mfma_f32_32x32x16_f16(kf, qf[kkq], sc[ni], 0, 0, 0);
            }
        __builtin_amdgcn_s_setprio(0);

        const bool maskp = (kv0 + 63) > qw;
#pragma unroll
        for (int ni = 0; ni < 2; ++ni)
#pragma unroll
            for (int r = 0; r < 16; ++r) {
                float p = __builtin_amdgcn_exp2f(sc[ni][r]);
                const int kvg = kv0 + ni * 32 + (r & 3) + 8 * (r >> 2) + 4 * h2;
                if (maskp && kvg > qg) p = 0.0f;
                sc[ni][r] = p;
            }

        __builtin_amdgcn_s_setprio(1);
#pragma unroll
        for (int ni = 0; ni < 2; ++ni) {
            uint32_t u[8];
#pragma unroll
            for (int m = 0; m < 8; ++m) {
                auto hp = __builtin_amdgcn_cvt_pkrtz(sc[ni][2 * m], sc[ni][2 * m + 1]);
                u[m] = __builtin_bit_cast(uint32_t, hp);
                l_part = __builtin_amdgcn_fdot2(__builtin_bit_cast(f16x2, u[m]), ones2, l_part, false);
            }
#pragma unroll
            for (int kkv = 0; kkv < 2; ++kkv) {
                auto sA = __builtin_amdgcn_permlane32_swap(u[4 * kkv + 0], u[4 * kkv + 2], false, false);
                auto sB = __builtin_amdgcn_permlane32_swap(u[4 * kkv + 1], u[4 * kkv + 3], false, false);
                u32x4 uv = { (uint32_t)sA[0], (uint32_t)sB[0], (uint32_t)sA[1], (uint32_t)sB[1] };
                f16x8 pf = __builtin_bit_cast(f16x8, uv);
                const int kg = ni * 2 + kkv;
#pragma unroll
                for (int dh = 0; dh < 2; ++dh) {
                    f16x8 vf = *(const f16x8*)&Vs[BUF][(((kg * 2 + h2) * 64) + dh * 32 + q32) * 8];
                    oacc[dh] = __builtin_amdgcn_mfma_f32_32x32x16_f16(pf, vf, oacc[dh], 0, 0, 0);
                }
            }
        }
        __builtin_amdgcn_s_setprio(0);
    };

    const int ntB = 2 * (qtB + 1);    // 18..32, even; strip B is the long one
    STAGE(0, 0);
    __syncthreads();
    for (int t = 0; t < ntB; t += 2) {
        STAGE(1, (t + 1) * 64);
        computeS(IC<0>{}, IC<0>{}, t);
        computeS(IC<0>{}, IC<1>{}, t);
        __syncthreads();
        if (t + 2 < ntB) STAGE(0, (t + 2) * 64);
        computeS(IC<1>{}, IC<0>{}, t + 1);
        computeS(IC<1>{}, IC<1>{}, t + 1);
        __syncthreads();
    }
#undef STAGE

    const int b = bh >> 4, h = bh & 15;
    const float invA = 1.0f / (lA + __shfl_xor(lA, 32));
    const float invB = 1.0f / (lB + __shfl_xor(lB, 32));
#pragma unroll
    for (int r = 0; r < 16; ++r) {
        const int crow = (r & 3) + 8 * (r >> 2) + 4 * h2;
        const float irA = __shfl(invA, crow);
        const float irB = __shfl(invB, crow);
#pragma unroll
        for (int dh = 0; dh < 2; ++dh) {
            ob[((long)b * S_ + qwA + crow) * E_ + h * HD_ + dh * 32 + q32] = (f16)(oaccA[dh][r] * irA);
            ob[((long)b * S_ + qwB + crow) * E_ + h * HD_ + dh * 32 + q32] = (f16)(oaccB[dh][r] * irB);
        }
    }
}

// ---------------------------------------------------------------- launch
extern "C" void kernel_launch(void* const* d_in, const int* in_sizes, int n_in,
                              void* d_out, int out_size, void* d_ws, size_t ws_size,
                              hipStream_t stream)
{
    (void)in_sizes; (void)n_in; (void)out_size; (void)ws_size;
    const float* x  = (const float*)d_in[0];
    const float* w1 = (const float*)d_in[1];
    const float* b1 = (const float*)d_in[2];
    const float* w2 = (const float*)d_in[3];
    const float* b2 = (const float*)d_in[4];
    float* out = (float*)d_out;

    char* ws = (char*)d_ws;
    f16* w1b = (f16*)ws;  ws += (size_t)3072 * 1024 * 2;
    f16* w2b = (f16*)ws;  ws += (size_t)1024 * 1024 * 2;
    f16* qb  = (f16*)ws;  ws += (size_t)BH_ * S_ * HD_ * 2;
    f16* kb  = (f16*)ws;  ws += (size_t)BH_ * S_ * HD_ * 2;
    f16* vtb = (f16*)ws;  ws += (size_t)BH_ * S_ * HD_ * 2;
    f16* ao  = (f16*)ws;  ws += (size_t)8192 * 1024 * 2;

    cvt_f32_to_f16<<<dim3(3072 * 1024 / 8 / 256), dim3(256), 0, stream>>>(w1, w1b, 3072 * 1024 / 8);
    cvt_f32_to_f16<<<dim3(1024 * 1024 / 8 / 256), dim3(256), 0, stream>>>(w2, w2b, 1024 * 1024 / 8);

    gemm_bt<0, 1><<<dim3(64 * 24), dim3(256), 0, stream>>>(
        nullptr, x, w1b, b1, nullptr, qb, kb, vtb, 8192, 3072, 1024);

    attn_fwd<<<dim3(8, 64), dim3(256), 0, stream>>>(qb, kb, vtb, ao);

    gemm_bt<1, 0><<<dim3(64 * 8), dim3(256), 0, stream>>>(
        ao, nullptr, w2b, b2, out, nullptr, nullptr, nullptr, 8192, 1024, 1024);
}

// Round 15
// 159.178 us; speedup vs baseline: 1.1462x; 1.1247x over previous
//
#include <hip/hip_runtime.h>
#include <stdint.h>

typedef _Float16 f16;
typedef _Float16 f16x2 __attribute__((ext_vector_type(2)));
typedef _Float16 f16x8 __attribute__((ext_vector_type(8)));
typedef float f32x4 __attribute__((ext_vector_type(4)));
typedef float f32x16 __attribute__((ext_vector_type(16)));
typedef uint32_t u32x4 __attribute__((ext_vector_type(4)));

#define B_   4
#define S_   2048
#define E_   1024
#define H_   16
#define HD_  64
#define BH_  (B_ * H_)

template <int N> struct IC { static constexpr int v = N; };

// ---------------------------------------------------------------- helpers
__device__ __forceinline__ void async_lds16(const void* g, void* l) {
    __builtin_amdgcn_global_load_lds(
        (__attribute__((address_space(1))) void*)(uintptr_t)g,
        (__attribute__((address_space(3))) void*)(uint32_t)(uintptr_t)l,
        16, 0, 0);
}

// ---------------------------------------------------------------- fp32 -> fp16
__global__ __launch_bounds__(256)
void cvt_f32_to_f16(const float* __restrict__ in, f16* __restrict__ out, int n8) {
    int i = blockIdx.x * 256 + threadIdx.x;
    if (i >= n8) return;
    const float4* p = (const float4*)in;
    float4 a = p[2 * i], b = p[2 * i + 1];
    f16x8 o;
    o[0] = (f16)a.x; o[1] = (f16)a.y; o[2] = (f16)a.z; o[3] = (f16)a.w;
    o[4] = (f16)b.x; o[5] = (f16)b.y; o[6] = (f16)b.z; o[7] = (f16)b.w;
    *(f16x8*)(out + 8 * (long)i) = o;
}

// ---------------------------------------------------------------- QKV GEMM, pipelined
// v6: BM=128 BN=256 BK=64, 8 waves (512 thr), 3-stage LDS rotation (144KB),
// prefetch distance 2, counted vmcnt(6) + raw s_barrier per K-tile (never
// drains to 0 mid-loop -> removes the 2-phase barrier-drain stall, T3/T4).
// Grid 768 = 3 balanced rounds/CU. Epilogue = proven v2 code (4x4 16x16
// frags/wave), q/k scatter + per-wave 64x64 LDS-transpose for vT.
__global__ __launch_bounds__(512)
void gemm_qkv(const f16* __restrict__ A, const f16* __restrict__ Bm,
              const float* __restrict__ bias,
              f16* __restrict__ qo, f16* __restrict__ ko, f16* __restrict__ vto)
{
    constexpr int K = 1024, N = 3072, NT = 16;
    __shared__ __align__(16) f16 L[3][(128 + 256) * 64];   // A: 8192 f16, B: 16384 f16 per buf
    const int tid = threadIdx.x, wave = tid >> 6, lane = tid & 63;
    const int lo = lane & 15, hi = lane >> 4;
    const int bid0 = blockIdx.x;
    const int bid = (bid0 & 7) * 96 + (bid0 >> 3);          // XCD swizzle, 768%8==0
    const int tm = bid / 12, tn = bid % 12;
    const long bm0 = (long)tm * 128, bn0 = (long)tn * 256;
    const int wr = (wave >> 2) * 64, wc = (wave & 3) * 64;

    // staging: 6 gload_lds per wave per tile; chunk c -> row=c>>3, src col-chunk=(c&7)^(row&7)
#define STAGE6(BUF, T)  do {                                                      \
    const long kk = (long)(T) * 64;                                               \
    _Pragma("unroll")                                                             \
    for (int j = 0; j < 2; ++j) {                                                 \
        const int c = j * 512 + tid;                                              \
        const int row = c >> 3, ch = c & 7;                                       \
        async_lds16(A + (bm0 + row) * K + kk + ((ch ^ (row & 7)) * 8),            \
                    &L[BUF][(j * 512 + wave * 64) * 8]);                          \
    }                                                                             \
    _Pragma("unroll")                                                             \
    for (int j = 0; j < 4; ++j) {                                                 \
        const int c = j * 512 + tid;                                              \
        const int row = c >> 3, ch = c & 7;                                       \
        async_lds16(Bm + (bn0 + row) * K + kk + ((ch ^ (row & 7)) * 8),           \
                    &L[BUF][8192 + (j * 512 + wave * 64) * 8]);                   \
    } } while (0)

    f32x4 acc[4][4] = {};

    auto tile = [&](auto bufc, int t) {
        constexpr int BUF = decltype(bufc)::v;
        constexpr int SBUF = (BUF + 2) % 3;
        if (t + 2 < NT) STAGE6(SBUF, t + 2);     // issue-early: 6 loads for tile t+2
        f16x8 af[2][4], bf[2][4];
#pragma unroll
        for (int kh = 0; kh < 2; ++kh) {
#pragma unroll
            for (int mi = 0; mi < 4; ++mi) {
                const int r = wr + mi * 16 + lo;
                af[kh][mi] = *(const f16x8*)&L[BUF][(r * 8 + ((kh * 4 + hi) ^ (r & 7))) * 8];
            }
#pragma unroll
            for (int ni = 0; ni < 4; ++ni) {
                const int r = wc + ni * 16 + lo;
                bf[kh][ni] = *(const f16x8*)&L[BUF][8192 + (r * 8 + ((kh * 4 + hi) ^ (r & 7))) * 8];
            }
        }
        __builtin_amdgcn_s_setprio(1);
#pragma unroll
        for (int kh = 0; kh < 2; ++kh)
#pragma unroll
            for (int mi = 0; mi < 4; ++mi)
#pragma unroll
                for (int ni = 0; ni < 4; ++ni)
                    acc[mi][ni] = __builtin_amdgcn_mfma_f32_16x16x32_f16(
                        af[kh][mi], bf[kh][ni], acc[mi][ni], 0, 0, 0);
        __builtin_amdgcn_s_setprio(0);
        // end of tile: guarantee tile t+1 landed; keep t+2's 6 loads in flight
        if (t + 2 < NT) asm volatile("s_waitcnt vmcnt(6)" ::: "memory");
        else            asm volatile("s_waitcnt vmcnt(0)" ::: "memory");
        __builtin_amdgcn_sched_barrier(0);
        __builtin_amdgcn_s_barrier();
    };

    // prologue: stage tiles 0,1; wait for tile 0 (6 newest = tile 1 stay in flight)
    STAGE6(0, 0);
    STAGE6(1, 1);
    asm volatile("s_waitcnt vmcnt(6)" ::: "memory");
    __builtin_amdgcn_sched_barrier(0);
    __builtin_amdgcn_s_barrier();
    for (int t = 0; t < 15; t += 3) {
        tile(IC<0>{}, t);
        tile(IC<1>{}, t + 1);
        tile(IC<2>{}, t + 2);
    }
    tile(IC<0>{}, 15);
#undef STAGE6

    // ---------------- epilogue (v2-proven, wr/wc remapped for 8 waves)
    const int which = (int)(bn0 >> 10);
    if (which < 2) {
#pragma unroll
        for (int mi = 0; mi < 4; ++mi)
#pragma unroll
            for (int ni = 0; ni < 4; ++ni)
#pragma unroll
                for (int j = 0; j < 4; ++j) {
                    const long r  = bm0 + wr + mi * 16 + 4 * hi + j;
                    const int  cn = (int)bn0 + wc + ni * 16 + lo;
                    const int  e = cn & 1023, h = e >> 6, d = e & 63;
                    const int  b = (int)(r >> 11), s = (int)(r & 2047);
                    const long bh = (long)b * H_ + h;
                    const f16 hv = (f16)(acc[mi][ni][j] + bias[cn]);
                    if (which == 0) qo[(bh * S_ + s) * HD_ + d] = hv;
                    else            ko[(bh * S_ + s) * HD_ + d] = hv;
                }
    } else {
        // v: per-wave 64x64 LDS transpose -> coalesced vT rows (last barrier done)
        f16* T = ((f16*)L) + wave * 4096;
#pragma unroll
        for (int ni = 0; ni < 4; ++ni) {
            const int dl = ni * 16 + lo;
            const int dx = dl & 7;
#pragma unroll
            for (int mi = 0; mi < 4; ++mi)
#pragma unroll
                for (int j = 0; j < 4; ++j) {
                    const int sl = mi * 16 + 4 * hi + j;
                    const int cn = (int)bn0 + wc + ni * 16 + lo;
                    T[dl * 64 + ((((sl >> 3) ^ dx) << 3) | (sl & 7))] =
                        (f16)(acc[mi][ni][j] + bias[cn]);
                }
        }
        const int b = (int)(bm0 >> 11);
        const int sbase = (int)(bm0 & 2047) + wr;
        const int h = ((int)(bn0 & 1023) + wc) >> 6;
        const long vbase = (long)(b * H_ + h) * HD_;
#pragma unroll
        for (int it = 0; it < 8; ++it) {
            const int d = it * 8 + (lane >> 3);
            const int schunk = lane & 7;
            u32x4 val = *(const u32x4*)&T[d * 64 + ((schunk ^ (d & 7)) << 3)];
            *(u32x4*)&vto[(vbase + d) * S_ + sbase + schunk * 8] = val;
        }
    }
}

// ---------------------------------------------------------------- GEMM v2 (out-proj)
// proven round-11 structure: 128x128, 16x16x32, static ping-pong, XOR swizzle.
template <int MODE>
__global__ __launch_bounds__(256)
void gemm_bt(const f16* __restrict__ A, const f16* __restrict__ Bm,
             const float* __restrict__ bias, float* __restrict__ Cf,
             f16* __restrict__ qo, f16* __restrict__ ko, f16* __restrict__ vto,
             int M, int N, int K)
{
    __shared__ __align__(16) f16 As[2][128 * 32];
    __shared__ __align__(16) f16 Bs[2][128 * 32];
    const int tid = threadIdx.x;
    const int wave = tid >> 6, lane = tid & 63;
    const int lo = lane & 15, hi = lane >> 4;
    const int ntn = N >> 7;
    const int tm = blockIdx.x / ntn, tn = blockIdx.x % ntn;
    const long bm0 = (long)tm << 7, bn0 = (long)tn << 7;
    const int wr = (wave >> 1) << 6, wc = (wave & 1) << 6;

    int srow[2], sxc[2];
#pragma unroll
    for (int p = 0; p < 2; ++p) {
        const int c = p * 256 + tid;
        srow[p] = c >> 2;
        sxc[p]  = (((c & 3) ^ ((c >> 3) & 3))) * 8;
    }

#define GSTAGE(BUF, K0)  do {                                                     \
    _Pragma("unroll")                                                             \
    for (int p = 0; p < 2; ++p) {                                                 \
        const int base = (p * 256 + wave * 64) * 8;                               \
        async_lds16(A  + (bm0 + srow[p]) * K + (K0) + sxc[p], &As[BUF][base]);    \
        async_lds16(Bm + (bn0 + srow[p]) * K + (K0) + sxc[p], &Bs[BUF][base]);    \
    } } while (0)

    f32x4 acc[4][4] = {};

    auto compute = [&](auto bufc) {
        constexpr int BUF = decltype(bufc)::v;
        f16x8 af[4], bf[4];
#pragma unroll
        for (int mi = 0; mi < 4; ++mi) {
            const int row = wr + mi * 16 + lo;
            af[mi] = *(const f16x8*)&As[BUF][row * 32 + ((hi ^ ((row >> 1) & 3)) * 8)];
        }
#pragma unroll
        for (int ni = 0; ni < 4; ++ni) {
            const int row = wc + ni * 16 + lo;
            bf[ni] = *(const f16x8*)&Bs[BUF][row * 32 + ((hi ^ ((row >> 1) & 3)) * 8)];
        }
        __builtin_amdgcn_s_setprio(1);
#pragma unroll
        for (int mi = 0; mi < 4; ++mi)
#pragma unroll
            for (int ni = 0; ni < 4; ++ni)
                acc[mi][ni] = __builtin_amdgcn_mfma_f32_16x16x32_f16(
                    af[mi], bf[ni], acc[mi][ni], 0, 0, 0);
        __builtin_amdgcn_s_setprio(0);
    };

    GSTAGE(0, 0);
    __syncthreads();
    for (int k0 = 0; k0 < K; k0 += 64) {
        GSTAGE(1, k0 + 32);
        compute(IC<0>{});
        __syncthreads();
        if (k0 + 64 < K) GSTAGE(0, k0 + 64);
        compute(IC<1>{});
        __syncthreads();
    }
#undef GSTAGE

    if (MODE == 1) {
#pragma unroll
        for (int mi = 0; mi < 4; ++mi)
#pragma unroll
            for (int ni = 0; ni < 4; ++ni)
#pragma unroll
                for (int j = 0; j < 4; ++j) {
                    const long r  = bm0 + wr + mi * 16 + 4 * hi + j;
                    const int  cn = (int)bn0 + wc + ni * 16 + lo;
                    Cf[r * N + cn] = acc[mi][ni][j] + bias[cn];
                }
        return;
    }
    (void)qo; (void)ko; (void)vto;
}

// ---------------------------------------------------------------- causal flash attention
// v9 (unchanged): 32x32 swapped QK, in-register P, chunk-major LDS, static
// ping-pong, strip pairing, raw v_exp_f32 softmax, dot2 row-sums.
__global__ __launch_bounds__(256)
void attn_fwd(const f16* __restrict__ qb, const f16* __restrict__ kb,
              const f16* __restrict__ vtb, f16* __restrict__ ob)
{
    __shared__ __align__(16) f16 Ks[2][64 * 64];
    __shared__ __align__(16) f16 Vs[2][64 * 64];
    const int tid = threadIdx.x, wave = tid >> 6, lane = tid & 63;
    const int q32 = lane & 31, h2 = lane >> 5;
    const int bh = blockIdx.y;
    const int qtA = blockIdx.x;
    const int qtB = 15 - qtA;
    const int qwA = qtA * 128 + wave * 32;
    const int qwB = qtB * 128 + wave * 32;
    const long krow0 = (long)bh * S_;
    const long vrow0 = (long)bh * HD_;

#define STAGE(BUF, KV)  do {                                                      \
    _Pragma("unroll")                                                             \
    for (int p = 0; p < 2; ++p) {                                                 \
        const int n = p * 256 + tid;                                              \
        const int base = (p * 256 + wave * 64) * 8;                               \
        async_lds16(kb  + (krow0 + (KV) + (n & 63)) * HD_ + (n >> 6) * 8, &Ks[BUF][base]); \
        async_lds16(vtb + (vrow0 + (n & 63)) * S_ + (KV) + (n >> 6) * 8, &Vs[BUF][base]);  \
    } } while (0)

    f16x8 qfA[4], qfB[4];
    const f16 sch = (f16)0.1803368801f;
#pragma unroll
    for (int kkq = 0; kkq < 4; ++kkq) {
        qfA[kkq] = *(const f16x8*)&qb[(krow0 + qwA + q32) * HD_ + kkq * 16 + h2 * 8];
        qfB[kkq] = *(const f16x8*)&qb[(krow0 + qwB + q32) * HD_ + kkq * 16 + h2 * 8];
#pragma unroll
        for (int e = 0; e < 8; ++e) { qfA[kkq][e] *= sch; qfB[kkq][e] *= sch; }
    }

    f32x16 oaccA[2] = {}, oaccB[2] = {};
    float lA = 0.f, lB = 0.f;
    const f16x2 ones2 = { (f16)1.0f, (f16)1.0f };

    auto computeS = [&](auto bufc, auto spc, int t) {
        constexpr int BUF = decltype(bufc)::v;
        constexpr int SP  = decltype(spc)::v;
        const int qw = SP ? qwB : qwA;
        const f16x8* qf = SP ? qfB : qfA;
        f32x16* oacc = SP ? oaccB : oaccA;
        float& l_part = SP ? lB : lA;
        const int kv0 = t * 64;
        if (kv0 > qw + 31) return;
        const int qg = qw + q32;

        f32x16 sc[2] = {};
        __builtin_amdgcn_s_setprio(1);
#pragma unroll
        for (int kkq = 0; kkq < 4; ++kkq)
#pragma unroll
            for (int ni = 0; ni < 2; ++ni) {
                f16x8 kf = *(const f16x8*)&Ks[BUF][(((kkq * 2 + h2) * 64) + ni * 32 + q32) * 8];
                sc[ni] = __builtin_amdgcn_mfma_f32_32x32x16_f16(kf, qf[kkq], sc[ni], 0, 0, 0);
            }
        __builtin_amdgcn_s_setprio(0);

        const bool maskp = (kv0 + 63) > qw;
#pragma unroll
        for (int ni = 0; ni < 2; ++ni)
#pragma unroll
            for (int r = 0; r < 16; ++r) {
                float p = __builtin_amdgcn_exp2f(sc[ni][r]);
                const int kvg = kv0 + ni * 32 + (r & 3) + 8 * (r >> 2) + 4 * h2;
                if (maskp && kvg > qg) p = 0.0f;
                sc[ni][r] = p;
            }

        __builtin_amdgcn_s_setprio(1);
#pragma unroll
        for (int ni = 0; ni < 2; ++ni) {
            uint32_t u[8];
#pragma unroll
            for (int m = 0; m < 8; ++m) {
                auto hp = __builtin_amdgcn_cvt_pkrtz(sc[ni][2 * m], sc[ni][2 * m + 1]);
                u[m] = __builtin_bit_cast(uint32_t, hp);
                l_part = __builtin_amdgcn_fdot2(__builtin_bit_cast(f16x2, u[m]), ones2, l_part, false);
            }
#pragma unroll
            for (int kkv = 0; kkv < 2; ++kkv) {
                auto sA = __builtin_amdgcn_permlane32_swap(u[4 * kkv + 0], u[4 * kkv + 2], false, false);
                auto sB = __builtin_amdgcn_permlane32_swap(u[4 * kkv + 1], u[4 * kkv + 3], false, false);
                u32x4 uv = { (uint32_t)sA[0], (uint32_t)sB[0], (uint32_t)sA[1], (uint32_t)sB[1] };
                f16x8 pf = __builtin_bit_cast(f16x8, uv);
                const int kg = ni * 2 + kkv;
#pragma unroll
                for (int dh = 0; dh < 2; ++dh) {
                    f16x8 vf = *(const f16x8*)&Vs[BUF][(((kg * 2 + h2) * 64) + dh * 32 + q32) * 8];
                    oacc[dh] = __builtin_amdgcn_mfma_f32_32x32x16_f16(pf, vf, oacc[dh], 0, 0, 0);
                }
            }
        }
        __builtin_amdgcn_s_setprio(0);
    };

    const int ntB = 2 * (qtB + 1);
    STAGE(0, 0);
    __syncthreads();
    for (int t = 0; t < ntB; t += 2) {
        STAGE(1, (t + 1) * 64);
        computeS(IC<0>{}, IC<0>{}, t);
        computeS(IC<0>{}, IC<1>{}, t);
        __syncthreads();
        if (t + 2 < ntB) STAGE(0, (t + 2) * 64);
        computeS(IC<1>{}, IC<0>{}, t + 1);
        computeS(IC<1>{}, IC<1>{}, t + 1);
        __syncthreads();
    }
#undef STAGE

    const int b = bh >> 4, h = bh & 15;
    const float invA = 1.0f / (lA + __shfl_xor(lA, 32));
    const float invB = 1.0f / (lB + __shfl_xor(lB, 32));
#pragma unroll
    for (int r = 0; r < 16; ++r) {
        const int crow = (r & 3) + 8 * (r >> 2) + 4 * h2;
        const float irA = __shfl(invA, crow);
        const float irB = __shfl(invB, crow);
#pragma unroll
        for (int dh = 0; dh < 2; ++dh) {
            ob[((long)b * S_ + qwA + crow) * E_ + h * HD_ + dh * 32 + q32] = (f16)(oaccA[dh][r] * irA);
            ob[((long)b * S_ + qwB + crow) * E_ + h * HD_ + dh * 32 + q32] = (f16)(oaccB[dh][r] * irB);
        }
    }
}

// ---------------------------------------------------------------- launch
extern "C" void kernel_launch(void* const* d_in, const int* in_sizes, int n_in,
                              void* d_out, int out_size, void* d_ws, size_t ws_size,
                              hipStream_t stream)
{
    (void)in_sizes; (void)n_in; (void)out_size; (void)ws_size;
    const float* x  = (const float*)d_in[0];
    const float* w1 = (const float*)d_in[1];
    const float* b1 = (const float*)d_in[2];
    const float* w2 = (const float*)d_in[3];
    const float* b2 = (const float*)d_in[4];
    float* out = (float*)d_out;

    char* ws = (char*)d_ws;
    f16* xb  = (f16*)ws;  ws += (size_t)8192 * 1024 * 2;
    f16* w1b = (f16*)ws;  ws += (size_t)3072 * 1024 * 2;
    f16* w2b = (f16*)ws;  ws += (size_t)1024 * 1024 * 2;
    f16* qb  = (f16*)ws;  ws += (size_t)BH_ * S_ * HD_ * 2;
    f16* kb  = (f16*)ws;  ws += (size_t)BH_ * S_ * HD_ * 2;
    f16* vtb = (f16*)ws;  ws += (size_t)BH_ * S_ * HD_ * 2;
    f16* ao  = (f16*)ws;  ws += (size_t)8192 * 1024 * 2;

    cvt_f32_to_f16<<<dim3(8192 * 1024 / 8 / 256), dim3(256), 0, stream>>>(x,  xb,  8192 * 1024 / 8);
    cvt_f32_to_f16<<<dim3(3072 * 1024 / 8 / 256), dim3(256), 0, stream>>>(w1, w1b, 3072 * 1024 / 8);
    cvt_f32_to_f16<<<dim3(1024 * 1024 / 8 / 256), dim3(256), 0, stream>>>(w2, w2b, 1024 * 1024 / 8);

    gemm_qkv<<<dim3(768), dim3(512), 0, stream>>>(xb, w1b, b1, qb, kb, vtb);

    attn_fwd<<<dim3(8, 64), dim3(256), 0, stream>>>(qb, kb, vtb, ao);

    gemm_bt<1><<<dim3(64 * 8), dim3(256), 0, stream>>>(
        ao, w2b, b2, out, nullptr, nullptr, nullptr, 8192, 1024, 1024);
}

// Round 16
// 148.822 us; speedup vs baseline: 1.2260x; 1.0696x over previous
//
#include <hip/hip_runtime.h>
#include <stdint.h>

typedef _Float16 f16;
typedef _Float16 f16x2 __attribute__((ext_vector_type(2)));
typedef _Float16 f16x8 __attribute__((ext_vector_type(8)));
typedef float f32x4 __attribute__((ext_vector_type(4)));
typedef float f32x16 __attribute__((ext_vector_type(16)));
typedef uint32_t u32x4 __attribute__((ext_vector_type(4)));

#define B_   4
#define S_   2048
#define E_   1024
#define H_   16
#define HD_  64
#define BH_  (B_ * H_)

template <int N> struct IC { static constexpr int v = N; };

// ---------------------------------------------------------------- helpers
__device__ __forceinline__ void async_lds16(const void* g, void* l) {
    __builtin_amdgcn_global_load_lds(
        (__attribute__((address_space(1))) void*)(uintptr_t)g,
        (__attribute__((address_space(3))) void*)(uint32_t)(uintptr_t)l,
        16, 0, 0);
}

// ---------------------------------------------------------------- fused fp32 -> fp16 (x, w1, w2)
__global__ __launch_bounds__(256)
void cvt3(const float* __restrict__ x, const float* __restrict__ w1,
          const float* __restrict__ w2, f16* __restrict__ xb,
          f16* __restrict__ w1b, f16* __restrict__ w2b)
{
    const long i = (long)blockIdx.x * 256 + threadIdx.x;   // 8-elem chunk id
    const float* src; f16* dst; long j;
    if (i < 1048576)      { src = x;  dst = xb;  j = i; }
    else if (i < 1441792) { src = w1; dst = w1b; j = i - 1048576; }
    else                  { src = w2; dst = w2b; j = i - 1441792; }
    const float4* p = (const float4*)src;
    float4 a = p[2 * j], b = p[2 * j + 1];
    f16x8 o;
    o[0] = (f16)a.x; o[1] = (f16)a.y; o[2] = (f16)a.z; o[3] = (f16)a.w;
    o[4] = (f16)b.x; o[5] = (f16)b.y; o[6] = (f16)b.z; o[7] = (f16)b.w;
    *(f16x8*)(dst + 8 * j) = o;
}

// ---------------------------------------------------------------- pipelined GEMM  C = A * B^T
// v6 (proven): BM=128 BN=256 BK=64, 8 waves, 3-stage LDS rotation (144KB),
// prefetch distance 2, counted vmcnt(6) + raw s_barrier (never drains mid-loop).
// MODE 0: QKV (N=3072), scatter epilogue (q/k + vT LDS-transpose).
// MODE 1: out-proj (N=1024), fp32 C + bias epilogue.
template <int MODE>
__global__ __launch_bounds__(512)
void gemm_pipe(const f16* __restrict__ A, const f16* __restrict__ Bm,
               const float* __restrict__ bias,
               f16* __restrict__ qo, f16* __restrict__ ko, f16* __restrict__ vto,
               float* __restrict__ Cf)
{
    constexpr int K = 1024, NT = 16;
    constexpr int N = (MODE == 0) ? 3072 : 1024;
    constexpr int NTN = N / 256;
    constexpr int NBLK = 64 * NTN;
    __shared__ __align__(16) f16 L[3][(128 + 256) * 64];
    const int tid = threadIdx.x, wave = tid >> 6, lane = tid & 63;
    const int lo = lane & 15, hi = lane >> 4;
    const int bid0 = blockIdx.x;
    const int bid = (bid0 & 7) * (NBLK / 8) + (bid0 >> 3);   // XCD swizzle (NBLK%8==0)
    const int tm = bid / NTN, tn = bid % NTN;
    const long bm0 = (long)tm * 128, bn0 = (long)tn * 256;
    const int wr = (wave >> 2) * 64, wc = (wave & 3) * 64;

#define STAGE6(BUF, T)  do {                                                      \
    const long kk = (long)(T) * 64;                                               \
    _Pragma("unroll")                                                             \
    for (int j = 0; j < 2; ++j) {                                                 \
        const int c = j * 512 + tid;                                              \
        const int row = c >> 3, ch = c & 7;                                       \
        async_lds16(A + (bm0 + row) * K + kk + ((ch ^ (row & 7)) * 8),            \
                    &L[BUF][(j * 512 + wave * 64) * 8]);                          \
    }                                                                             \
    _Pragma("unroll")                                                             \
    for (int j = 0; j < 4; ++j) {                                                 \
        const int c = j * 512 + tid;                                              \
        const int row = c >> 3, ch = c & 7;                                       \
        async_lds16(Bm + (bn0 + row) * K + kk + ((ch ^ (row & 7)) * 8),           \
                    &L[BUF][8192 + (j * 512 + wave * 64) * 8]);                   \
    } } while (0)

    f32x4 acc[4][4] = {};

    auto tile = [&](auto bufc, int t) {
        constexpr int BUF = decltype(bufc)::v;
        constexpr int SBUF = (BUF + 2) % 3;
        if (t + 2 < NT) STAGE6(SBUF, t + 2);
        f16x8 af[2][4], bf[2][4];
#pragma unroll
        for (int kh = 0; kh < 2; ++kh) {
#pragma unroll
            for (int mi = 0; mi < 4; ++mi) {
                const int r = wr + mi * 16 + lo;
                af[kh][mi] = *(const f16x8*)&L[BUF][(r * 8 + ((kh * 4 + hi) ^ (r & 7))) * 8];
            }
#pragma unroll
            for (int ni = 0; ni < 4; ++ni) {
                const int r = wc + ni * 16 + lo;
                bf[kh][ni] = *(const f16x8*)&L[BUF][8192 + (r * 8 + ((kh * 4 + hi) ^ (r & 7))) * 8];
            }
        }
        __builtin_amdgcn_s_setprio(1);
#pragma unroll
        for (int kh = 0; kh < 2; ++kh)
#pragma unroll
            for (int mi = 0; mi < 4; ++mi)
#pragma unroll
                for (int ni = 0; ni < 4; ++ni)
                    acc[mi][ni] = __builtin_amdgcn_mfma_f32_16x16x32_f16(
                        af[kh][mi], bf[kh][ni], acc[mi][ni], 0, 0, 0);
        __builtin_amdgcn_s_setprio(0);
        if (t + 2 < NT) asm volatile("s_waitcnt vmcnt(6)" ::: "memory");
        else            asm volatile("s_waitcnt vmcnt(0)" ::: "memory");
        __builtin_amdgcn_sched_barrier(0);
        __builtin_amdgcn_s_barrier();
    };

    STAGE6(0, 0);
    STAGE6(1, 1);
    asm volatile("s_waitcnt vmcnt(6)" ::: "memory");
    __builtin_amdgcn_sched_barrier(0);
    __builtin_amdgcn_s_barrier();
    for (int t = 0; t < 15; t += 3) {
        tile(IC<0>{}, t);
        tile(IC<1>{}, t + 1);
        tile(IC<2>{}, t + 2);
    }
    tile(IC<0>{}, 15);
#undef STAGE6

    if (MODE == 1) {
#pragma unroll
        for (int mi = 0; mi < 4; ++mi)
#pragma unroll
            for (int ni = 0; ni < 4; ++ni)
#pragma unroll
                for (int j = 0; j < 4; ++j) {
                    const long r  = bm0 + wr + mi * 16 + 4 * hi + j;
                    const int  cn = (int)bn0 + wc + ni * 16 + lo;
                    Cf[r * N + cn] = acc[mi][ni][j] + bias[cn];
                }
        return;
    }

    const int which = (int)(bn0 >> 10);
    if (which < 2) {
#pragma unroll
        for (int mi = 0; mi < 4; ++mi)
#pragma unroll
            for (int ni = 0; ni < 4; ++ni)
#pragma unroll
                for (int j = 0; j < 4; ++j) {
                    const long r  = bm0 + wr + mi * 16 + 4 * hi + j;
                    const int  cn = (int)bn0 + wc + ni * 16 + lo;
                    const int  e = cn & 1023, h = e >> 6, d = e & 63;
                    const int  b = (int)(r >> 11), s = (int)(r & 2047);
                    const long bh = (long)b * H_ + h;
                    const f16 hv = (f16)(acc[mi][ni][j] + bias[cn]);
                    if (which == 0) qo[(bh * S_ + s) * HD_ + d] = hv;
                    else            ko[(bh * S_ + s) * HD_ + d] = hv;
                }
    } else {
        f16* T = ((f16*)L) + wave * 4096;
#pragma unroll
        for (int ni = 0; ni < 4; ++ni) {
            const int dl = ni * 16 + lo;
            const int dx = dl & 7;
#pragma unroll
            for (int mi = 0; mi < 4; ++mi)
#pragma unroll
                for (int j = 0; j < 4; ++j) {
                    const int sl = mi * 16 + 4 * hi + j;
                    const int cn = (int)bn0 + wc + ni * 16 + lo;
                    T[dl * 64 + ((((sl >> 3) ^ dx) << 3) | (sl & 7))] =
                        (f16)(acc[mi][ni][j] + bias[cn]);
                }
        }
        const int b = (int)(bm0 >> 11);
        const int sbase = (int)(bm0 & 2047) + wr;
        const int h = ((int)(bn0 & 1023) + wc) >> 6;
        const long vbase = (long)(b * H_ + h) * HD_;
#pragma unroll
        for (int it = 0; it < 8; ++it) {
            const int d = it * 8 + (lane >> 3);
            const int schunk = lane & 7;
            u32x4 val = *(const u32x4*)&T[d * 64 + ((schunk ^ (d & 7)) << 3)];
            *(u32x4*)&vto[(vbase + d) * S_ + sbase + schunk * 8] = val;
        }
    }
}

// ---------------------------------------------------------------- causal flash attention
// v10 = v9 + XCD-locality grid: grid (64,8) so flat id % 8 = bh%8 -> all 8
// strip-blocks of a bh share one XCD's L2 (2MB KV working set < 4MB) instead
// of landing on 8 different XCDs (id was qtA + 8*bh). FETCH 110MB -> ~30MB.
__global__ __launch_bounds__(256)
void attn_fwd(const f16* __restrict__ qb, const f16* __restrict__ kb,
              const f16* __restrict__ vtb, f16* __restrict__ ob)
{
    __shared__ __align__(16) f16 Ks[2][64 * 64];
    __shared__ __align__(16) f16 Vs[2][64 * 64];
    const int tid = threadIdx.x, wave = tid >> 6, lane = tid & 63;
    const int q32 = lane & 31, h2 = lane >> 5;
    const int bh = blockIdx.x;           // XCD = id%8 = bh%8
    const int qtA = blockIdx.y;          // 0..7
    const int qtB = 15 - qtA;
    const int qwA = qtA * 128 + wave * 32;
    const int qwB = qtB * 128 + wave * 32;
    const long krow0 = (long)bh * S_;
    const long vrow0 = (long)bh * HD_;

#define STAGE(BUF, KV)  do {                                                      \
    _Pragma("unroll")                                                             \
    for (int p = 0; p < 2; ++p) {                                                 \
        const int n = p * 256 + tid;                                              \
        const int base = (p * 256 + wave * 64) * 8;                               \
        async_lds16(kb  + (krow0 + (KV) + (n & 63)) * HD_ + (n >> 6) * 8, &Ks[BUF][base]); \
        async_lds16(vtb + (vrow0 + (n & 63)) * S_ + (KV) + (n >> 6) * 8, &Vs[BUF][base]);  \
    } } while (0)

    f16x8 qfA[4], qfB[4];
    const f16 sch = (f16)0.1803368801f;
#pragma unroll
    for (int kkq = 0; kkq < 4; ++kkq) {
        qfA[kkq] = *(const f16x8*)&qb[(krow0 + qwA + q32) * HD_ + kkq * 16 + h2 * 8];
        qfB[kkq] = *(const f16x8*)&qb[(krow0 + qwB + q32) * HD_ + kkq * 16 + h2 * 8];
#pragma unroll
        for (int e = 0; e < 8; ++e) { qfA[kkq][e] *= sch; qfB[kkq][e] *= sch; }
    }

    f32x16 oaccA[2] = {}, oaccB[2] = {};
    float lA = 0.f, lB = 0.f;
    const f16x2 ones2 = { (f16)1.0f, (f16)1.0f };

    auto computeS = [&](auto bufc, auto spc, int t) {
        constexpr int BUF = decltype(bufc)::v;
        constexpr int SP  = decltype(spc)::v;
        const int qw = SP ? qwB : qwA;
        const f16x8* qf = SP ? qfB : qfA;
        f32x16* oacc = SP ? oaccB : oaccA;
        float& l_part = SP ? lB : lA;
        const int kv0 = t * 64;
        if (kv0 > qw + 31) return;
        const int qg = qw + q32;

        f32x16 sc[2] = {};
        __builtin_amdgcn_s_setprio(1);
#pragma unroll
        for (int kkq = 0; kkq < 4; ++kkq)
#pragma unroll
            for (int ni = 0; ni < 2; ++ni) {
                f16x8 kf = *(const f16x8*)&Ks[BUF][(((kkq * 2 + h2) * 64) + ni * 32 + q32) * 8];
                sc[ni] = __builtin_amdgcn_mfma_f32_32x32x16_f16(kf, qf[kkq], sc[ni], 0, 0, 0);
            }
        __builtin_amdgcn_s_setprio(0);

        const bool maskp = (kv0 + 63) > qw;
#pragma unroll
        for (int ni = 0; ni < 2; ++ni)
#pragma unroll
            for (int r = 0; r < 16; ++r) {
                float p = __builtin_amdgcn_exp2f(sc[ni][r]);
                const int kvg = kv0 + ni * 32 + (r & 3) + 8 * (r >> 2) + 4 * h2;
                if (maskp && kvg > qg) p = 0.0f;
                sc[ni][r] = p;
            }

        __builtin_amdgcn_s_setprio(1);
#pragma unroll
        for (int ni = 0; ni < 2; ++ni) {
            uint32_t u[8];
#pragma unroll
            for (int m = 0; m < 8; ++m) {
                auto hp = __builtin_amdgcn_cvt_pkrtz(sc[ni][2 * m], sc[ni][2 * m + 1]);
                u[m] = __builtin_bit_cast(uint32_t, hp);
                l_part = __builtin_amdgcn_fdot2(__builtin_bit_cast(f16x2, u[m]), ones2, l_part, false);
            }
#pragma unroll
            for (int kkv = 0; kkv < 2; ++kkv) {
                auto sA = __builtin_amdgcn_permlane32_swap(u[4 * kkv + 0], u[4 * kkv + 2], false, false);
                auto sB = __builtin_amdgcn_permlane32_swap(u[4 * kkv + 1], u[4 * kkv + 3], false, false);
                u32x4 uv = { (uint32_t)sA[0], (uint32_t)sB[0], (uint32_t)sA[1], (uint32_t)sB[1] };
                f16x8 pf = __builtin_bit_cast(f16x8, uv);
                const int kg = ni * 2 + kkv;
#pragma unroll
                for (int dh = 0; dh < 2; ++dh) {
                    f16x8 vf = *(const f16x8*)&Vs[BUF][(((kg * 2 + h2) * 64) + dh * 32 + q32) * 8];
                    oacc[dh] = __builtin_amdgcn_mfma_f32_32x32x16_f16(pf, vf, oacc[dh], 0, 0, 0);
                }
            }
        }
        __builtin_amdgcn_s_setprio(0);
    };

    const int ntB = 2 * (qtB + 1);
    STAGE(0, 0);
    __syncthreads();
    for (int t = 0; t < ntB; t += 2) {
        STAGE(1, (t + 1) * 64);
        computeS(IC<0>{}, IC<0>{}, t);
        computeS(IC<0>{}, IC<1>{}, t);
        __syncthreads();
        if (t + 2 < ntB) STAGE(0, (t + 2) * 64);
        computeS(IC<1>{}, IC<0>{}, t + 1);
        computeS(IC<1>{}, IC<1>{}, t + 1);
        __syncthreads();
    }
#undef STAGE

    const int b = bh >> 4, h = bh & 15;
    const float invA = 1.0f / (lA + __shfl_xor(lA, 32));
    const float invB = 1.0f / (lB + __shfl_xor(lB, 32));
#pragma unroll
    for (int r = 0; r < 16; ++r) {
        const int crow = (r & 3) + 8 * (r >> 2) + 4 * h2;
        const float irA = __shfl(invA, crow);
        const float irB = __shfl(invB, crow);
#pragma unroll
        for (int dh = 0; dh < 2; ++dh) {
            ob[((long)b * S_ + qwA + crow) * E_ + h * HD_ + dh * 32 + q32] = (f16)(oaccA[dh][r] * irA);
            ob[((long)b * S_ + qwB + crow) * E_ + h * HD_ + dh * 32 + q32] = (f16)(oaccB[dh][r] * irB);
        }
    }
}

// ---------------------------------------------------------------- launch
extern "C" void kernel_launch(void* const* d_in, const int* in_sizes, int n_in,
                              void* d_out, int out_size, void* d_ws, size_t ws_size,
                              hipStream_t stream)
{
    (void)in_sizes; (void)n_in; (void)out_size; (void)ws_size;
    const float* x  = (const float*)d_in[0];
    const float* w1 = (const float*)d_in[1];
    const float* b1 = (const float*)d_in[2];
    const float* w2 = (const float*)d_in[3];
    const float* b2 = (const float*)d_in[4];
    float* out = (float*)d_out;

    char* ws = (char*)d_ws;
    f16* xb  = (f16*)ws;  ws += (size_t)8192 * 1024 * 2;
    f16* w1b = (f16*)ws;  ws += (size_t)3072 * 1024 * 2;
    f16* w2b = (f16*)ws;  ws += (size_t)1024 * 1024 * 2;
    f16* qb  = (f16*)ws;  ws += (size_t)BH_ * S_ * HD_ * 2;
    f16* kb  = (f16*)ws;  ws += (size_t)BH_ * S_ * HD_ * 2;
    f16* vtb = (f16*)ws;  ws += (size_t)BH_ * S_ * HD_ * 2;
    f16* ao  = (f16*)ws;  ws += (size_t)8192 * 1024 * 2;

    cvt3<<<dim3(6144), dim3(256), 0, stream>>>(x, w1, w2, xb, w1b, w2b);

    gemm_pipe<0><<<dim3(768), dim3(512), 0, stream>>>(xb, w1b, b1, qb, kb, vtb, nullptr);

    attn_fwd<<<dim3(64, 8), dim3(256), 0, stream>>>(qb, kb, vtb, ao);

    gemm_pipe<1><<<dim3(256), dim3(512), 0, stream>>>(ao, w2b, b2, nullptr, nullptr, nullptr, out);
}